// Round 4
// baseline (518.975 us; speedup 1.0000x reference)
//
#include <hip/hip_runtime.h>
#include <math.h>

#define ALPHA 0.42f
#define H 1024
#define W 1024
#define NB 16
#define NCH 48
#define BH 64           // rows per band (per block)

typedef float nfloat4 __attribute__((ext_vector_type(4)));

__device__ __forceinline__ float sigf(float x) {
    return 1.0f / (1.0f + __expf(-x));
}

// ---------------------------------------------------------------------------
// score_kernel: register-rolling vertical walk; no LDS in the hot loop.
// Block = 4 waves; wave w owns cols [256w, 256w+256); lane owns 4 cols.
// Rings of 8 (static indices via unroll-8): raw loads (2-deep prefetch),
// halo loads, sigmoid rows (cols c4-1..c4+4), horizontal 7-sums.
// score = ALPHA*sum(edge) + (1-ALPHA)*sum((m-mean)^2 * fx*fy/49)
// ---------------------------------------------------------------------------
__global__ __launch_bounds__(256, 3)
void score_kernel(const float* __restrict__ logits, float* __restrict__ scores) {
    __shared__ float red[4];
    const int tid  = threadIdx.x;
    const int lane = tid & 63;
    const int wvi  = tid >> 6;
    const int ch   = blockIdx.y;
    const int band = blockIdx.x * BH;
    const int gx0  = wvi * 256 + lane * 4;
    const float* img = logits + (size_t)ch * (H * W);

    const bool isL = (lane == 0);
    const bool isR = (lane == 63);
    const bool haloActive = isL || isR;
    const int  hx_raw = isL ? (gx0 - 4) : (gx0 + 4);
    const bool hValid = (hx_raw >= 0) && (hx_raw <= W - 4);
    const int  hx = min(max(hx_raw, 0), W - 4);

    float fxf[4];
    #pragma unroll
    for (int j = 0; j < 4; ++j) {
        int gx = gx0 + j;
        fxf[j] = (float)(7 - max(0, 3 - gx) - max(0, gx - (W - 4)));
    }

    float4 vb[8];           // raw row loads
    float4 hb[8];           // halo row loads (lanes 0/63 only)
    float  sr[8][6];        // sigmoid rows, cols c4-1..c4+4
    float  rsr[8][4];       // horizontal 7-sums
    float  vs0 = 0.f, vs1 = 0.f, vs2 = 0.f, vs3 = 0.f;
    #pragma unroll
    for (int k = 0; k < 8; ++k)
        rsr[k][0] = rsr[k][1] = rsr[k][2] = rsr[k][3] = 0.f;

    float acc = 0.f;

    auto loadrow = [&](int g, int slot) {
        int gc = min(max(g, 0), H - 1);
        const float* p = img + (size_t)gc * W;
        vb[slot] = *(const float4*)(p + gx0);
        if (haloActive) hb[slot] = *(const float4*)(p + hx);
    };

    auto ingest = [&](int g, int slot, int oldslot) {
        float4 raw = vb[slot];
        bool rowv = (g >= 0) && (g < H);   // wave-uniform
        float s0 = 0.f, s1 = 0.f, s2 = 0.f, s3 = 0.f;
        if (rowv) { s0 = sigf(raw.x); s1 = sigf(raw.y); s2 = sigf(raw.z); s3 = sigf(raw.w); }
        float l1 = __shfl_up(s1, 1), l2 = __shfl_up(s2, 1), l3 = __shfl_up(s3, 1);
        float r0 = __shfl_down(s0, 1), r1 = __shfl_down(s1, 1), r2 = __shfl_down(s2, 1);
        if (haloActive) {
            float4 h = hb[slot];
            bool hv = hValid && rowv;
            float h0 = hv ? sigf(h.x) : 0.f;
            float h1 = hv ? sigf(h.y) : 0.f;
            float h2 = hv ? sigf(h.z) : 0.f;
            float h3 = hv ? sigf(h.w) : 0.f;
            if (isL) { l1 = h1; l2 = h2; l3 = h3; }
            else     { r0 = h0; r1 = h1; r2 = h2; }
        }
        float rs0 = l1 + l2 + l3 + s0 + s1 + s2 + s3;
        float rs1 = rs0 - l1 + r0;
        float rs2 = rs1 - l2 + r1;
        float rs3 = rs2 - l3 + r2;
        vs0 += rs0 - rsr[oldslot][0];
        vs1 += rs1 - rsr[oldslot][1];
        vs2 += rs2 - rsr[oldslot][2];
        vs3 += rs3 - rsr[oldslot][3];
        rsr[slot][0] = rs0; rsr[slot][1] = rs1; rsr[slot][2] = rs2; rsr[slot][3] = rs3;
        sr[slot][0] = l3; sr[slot][1] = s0; sr[slot][2] = s1;
        sr[slot][3] = s2; sr[slot][4] = s3; sr[slot][5] = r0;
    };

    auto emit = [&](int y, int sA, int sB, int sC) {
        int Y = band + y;
        float wvv = (1.0f - ALPHA) * (1.0f / 49.0f) *
                    (float)(7 - max(0, 3 - Y) - max(0, Y - (H - 4)));
        const float* A  = sr[sA];
        const float* Bv = sr[sB];
        const float* Cv = sr[sC];
        float vsv[4] = {vs0, vs1, vs2, vs3};
        #pragma unroll
        for (int j = 0; j < 4; ++j) {
            float a00 = A[j],  a01 = A[j + 1],  a02 = A[j + 2];
            float a10 = Bv[j], a11 = Bv[j + 1], a12 = Bv[j + 2];
            float a20 = Cv[j], a21 = Cv[j + 1], a22 = Cv[j + 2];
            float sgx = (a00 - a02) + 2.f * (a10 - a12) + (a20 - a22);
            float sgy = (a00 + 2.f * a01 + a02) - (a20 + 2.f * a21 + a22);
            float lp  = a01 + a10 + a12 + a21 - 4.f * a11;
            float edge = sqrtf(sgx * sgx + sgy * sgy) + 0.5f * fabsf(lp);
            float mean = vsv[j] * (1.f / 49.f);
            float d = a11 - mean;
            acc += ALPHA * edge + wvv * fxf[j] * (d * d);
        }
    };

    // preload raw rows band-3, band-2 (slots 0,1)
    loadrow(band - 3, 0);
    loadrow(band - 2, 1);

    // prologue: ingest rows band-3..band+2 (slots 0..5), keep 2-deep prefetch
    #pragma unroll
    for (int p = 0; p < 6; ++p) {
        loadrow(band - 1 + p, p + 2);
        ingest(band - 3 + p, p, (p + 1) & 7);
    }

    // main: ingest row band+3+y (slot (y+6)&7), prefetch row band+5+y (slot y&7),
    // emit row band+y from sigmoid rows (y+2),(y+3),(y+4) &7
    for (int yy = 0; yy < BH; yy += 8) {
        #pragma unroll
        for (int k = 0; k < 8; ++k) {
            int y = yy + k;
            loadrow(band + 5 + y, y & 7);
            ingest(band + 3 + y, (y + 6) & 7, (y + 7) & 7);
            emit(y, (y + 2) & 7, (y + 3) & 7, (y + 4) & 7);
        }
    }

    // wave reduce then block reduce
    #pragma unroll
    for (int off = 32; off > 0; off >>= 1) acc += __shfl_down(acc, off);
    if (lane == 0) red[wvi] = acc;
    __syncthreads();
    if (tid == 0) atomicAdd(&scores[ch], red[0] + red[1] + red[2] + red[3]);
}

// ---------------------------------------------------------------------------
// fuse_kernel: out[b] = sum_s w[b,s] * logits[b,s]; 4 float4/thread,
// nontemporal stores to keep logits L3-resident.
// ---------------------------------------------------------------------------
__global__ __launch_bounds__(256)
void fuse_kernel(const float* __restrict__ logits,
                 const float* __restrict__ scores,
                 const float* __restrict__ lw,
                 float* __restrict__ out) {
    const int b = blockIdx.y;
    const size_t HW4 = (size_t)H * W / 4;

    float l0 = lw[0], l1 = lw[1], l2 = lw[2];
    float mx = fmaxf(l0, fmaxf(l1, l2));
    float e0 = __expf(l0 - mx), e1 = __expf(l1 - mx), e2 = __expf(l2 - mx);
    float inv = 1.f / (e0 + e1 + e2);
    float s0 = scores[b * 3 + 0], s1 = scores[b * 3 + 1], s2 = scores[b * 3 + 2];
    float itot = 1.f / (s0 + s1 + s2 + 1e-6f);
    float w0 = 0.5f * (s0 * itot + e0 * inv);
    float w1 = 0.5f * (s1 * itot + e1 * inv);
    float w2 = 0.5f * (s2 * itot + e2 * inv);

    const float4* base = (const float4*)(logits + (size_t)b * 3 * H * W);
    nfloat4* ob = (nfloat4*)(out + (size_t)b * H * W);
    size_t i0 = (size_t)blockIdx.x * 1024 + threadIdx.x;
    #pragma unroll
    for (int k = 0; k < 4; ++k) {
        size_t i = i0 + (size_t)k * 256;
        float4 x0 = base[i];
        float4 x1 = base[i + HW4];
        float4 x2 = base[i + 2 * HW4];
        nfloat4 o;
        o.x = x0.x * w0 + x1.x * w1 + x2.x * w2;
        o.y = x0.y * w0 + x1.y * w1 + x2.y * w2;
        o.z = x0.z * w0 + x1.z * w1 + x2.z * w2;
        o.w = x0.w * w0 + x1.w * w1 + x2.w * w2;
        __builtin_nontemporal_store(o, &ob[i]);
    }
}

extern "C" void kernel_launch(void* const* d_in, const int* in_sizes, int n_in,
                              void* d_out, int out_size, void* d_ws, size_t ws_size,
                              hipStream_t stream) {
    const float* logits = (const float*)d_in[0];
    const float* lw     = (const float*)d_in[1];
    float* out    = (float*)d_out;
    float* scores = (float*)d_ws;    // 48 floats

    (void)hipMemsetAsync(d_ws, 0, NCH * sizeof(float), stream);

    dim3 g1(H / BH, NCH);            // (16, 48) = 768 blocks = 3/CU exactly
    score_kernel<<<g1, 256, 0, stream>>>(logits, scores);

    dim3 g2((H * W / 4) / 1024, NB); // (256, 16)
    fuse_kernel<<<g2, 256, 0, stream>>>(logits, scores, lw, out);
}

// Round 5
// 406.118 us; speedup vs baseline: 1.2779x; 1.2779x over previous
//
#include <hip/hip_runtime.h>
#include <math.h>

#define ALPHA 0.42f
#define H 1024
#define W 1024
#define NB 16
#define NCH 48
#define BH 32           // rows per band (per block)

typedef float nfloat4 __attribute__((ext_vector_type(4)));

__device__ __forceinline__ float sigf(float x) {
    return 1.0f / (1.0f + __expf(-x));
}

// ---------------------------------------------------------------------------
// score_kernel: register-rolling vertical walk, no LDS in hot loop, no spills.
// Wave w owns cols [256w, 256w+256); lane owns 4 cols. Scalar rings indexed
// by compile-time constants only (SROA-safe); launch_bounds(256,2) gives a
// 256-VGPR cap so the ~140-reg working set stays in registers.
// score = ALPHA*sum(edge) + (1-ALPHA)*sum((m-mean7x7)^2 * fx*fy/49)
// ---------------------------------------------------------------------------
__global__ __launch_bounds__(256, 2)
void score_kernel(const float* __restrict__ logits, float* __restrict__ scores) {
    __shared__ float red[4];
    const int tid  = threadIdx.x;
    const int lane = tid & 63;
    const int wvi  = tid >> 6;
    const int ch   = blockIdx.y;
    const int band = blockIdx.x * BH;
    const int gx0  = wvi * 256 + lane * 4;
    const float* img = logits + (size_t)ch * (H * W);

    const bool isL = (lane == 0);
    const bool isR = (lane == 63);
    const bool haloActive = isL || isR;
    const int  hx_raw = isL ? (gx0 - 4) : (gx0 + 4);
    const bool hValid = (hx_raw >= 0) && (hx_raw <= W - 4);
    const int  hx = min(max(hx_raw, 0), W - 4);

    const float fxf0 = (float)(7 - max(0, 3 - (gx0 + 0)) - max(0, (gx0 + 0) - (W - 4)));
    const float fxf1 = (float)(7 - max(0, 3 - (gx0 + 1)) - max(0, (gx0 + 1) - (W - 4)));
    const float fxf2 = (float)(7 - max(0, 3 - (gx0 + 2)) - max(0, (gx0 + 2) - (W - 4)));
    const float fxf3 = (float)(7 - max(0, 3 - (gx0 + 3)) - max(0, (gx0 + 3) - (W - 4)));

    float4 vb[4];                 // raw row loads (prefetch ring, depth 2)
    float4 hb[4];                 // halo loads (lanes 0/63)
    float srm[8], sr0[8], sr1[8], sr2[8], sr3[8], srp[8];  // sigmoid rows c4-1..c4+4
    float rsA[8], rsB[8], rsC[8], rsD[8];                  // horizontal 7-sums
    float vs0 = 0.f, vs1 = 0.f, vs2 = 0.f, vs3 = 0.f;
    float acc = 0.f;
    #pragma unroll
    for (int k = 0; k < 8; ++k) { rsA[k] = rsB[k] = rsC[k] = rsD[k] = 0.f; }

    auto LOAD = [&](int g, int slot4) {
        int gc = min(max(g, 0), H - 1);
        const float* p = img + (size_t)gc * W;
        vb[slot4] = *(const float4*)(p + gx0);
        if (haloActive) hb[slot4] = *(const float4*)(p + hx);
    };

    auto INGEST = [&](int g, int slot4, int slot8) {
        float4 raw = vb[slot4];
        bool rowv = (g >= 0) && (g < H);                  // wave-uniform
        float s0v = 0.f, s1v = 0.f, s2v = 0.f, s3v = 0.f;
        if (rowv) { s0v = sigf(raw.x); s1v = sigf(raw.y); s2v = sigf(raw.z); s3v = sigf(raw.w); }
        float l1 = __shfl_up(s1v, 1), l2 = __shfl_up(s2v, 1), l3 = __shfl_up(s3v, 1);
        float r0 = __shfl_down(s0v, 1), r1 = __shfl_down(s1v, 1), r2 = __shfl_down(s2v, 1);
        if (haloActive) {
            float4 h = hb[slot4];
            bool hv = hValid && rowv;
            float h0 = hv ? sigf(h.x) : 0.f;
            float h1 = hv ? sigf(h.y) : 0.f;
            float h2 = hv ? sigf(h.z) : 0.f;
            float h3 = hv ? sigf(h.w) : 0.f;
            if (isL) { l1 = h1; l2 = h2; l3 = h3; }
            else     { r0 = h0; r1 = h1; r2 = h2; }
        }
        float a = l1 + l2 + l3 + s0v + s1v + s2v + s3v;   // window @ col c4
        float b = a - l1 + r0;
        float c = b - l2 + r1;
        float d = c - l3 + r2;
        int old = (slot8 + 1) & 7;                        // row r-7
        vs0 += a - rsA[old]; vs1 += b - rsB[old];
        vs2 += c - rsC[old]; vs3 += d - rsD[old];
        rsA[slot8] = a; rsB[slot8] = b; rsC[slot8] = c; rsD[slot8] = d;
        srm[slot8] = l3; sr0[slot8] = s0v; sr1[slot8] = s1v;
        sr2[slot8] = s2v; sr3[slot8] = s3v; srp[slot8] = r0;
    };

#define PIX(a00,a01,a02,a10,a11,a12,a20,a21,a22,vsv,fx) do {            \
        float sgx = ((a00) - (a02)) + 2.f * ((a10) - (a12)) + ((a20) - (a22)); \
        float sgy = ((a00) + 2.f * (a01) + (a02)) - ((a20) + 2.f * (a21) + (a22)); \
        float lp  = (a01) + (a10) + (a12) + (a21) - 4.f * (a11);        \
        float edge = sqrtf(sgx * sgx + sgy * sgy) + 0.5f * fabsf(lp);   \
        float mean = (vsv) * (1.f / 49.f);                              \
        float dd = (a11) - mean;                                        \
        acc += ALPHA * edge + wvv * (fx) * (dd * dd);                   \
    } while (0)

    auto EMIT = [&](int y, int sA, int sB, int sC) {
        int Y = band + y;
        float wvv = (1.0f - ALPHA) * (1.0f / 49.0f) *
                    (float)(7 - max(0, 3 - Y) - max(0, Y - (H - 4)));
        float A0 = srm[sA], A1 = sr0[sA], A2 = sr1[sA], A3 = sr2[sA], A4 = sr3[sA], A5 = srp[sA];
        float B0 = srm[sB], B1 = sr0[sB], B2 = sr1[sB], B3 = sr2[sB], B4 = sr3[sB], B5 = srp[sB];
        float C0 = srm[sC], C1 = sr0[sC], C2 = sr1[sC], C3 = sr2[sC], C4 = sr3[sC], C5 = srp[sC];
        PIX(A0, A1, A2, B0, B1, B2, C0, C1, C2, vs0, fxf0);
        PIX(A1, A2, A3, B1, B2, B3, C1, C2, C3, vs1, fxf1);
        PIX(A2, A3, A4, B2, B3, B4, C2, C3, C4, vs2, fxf2);
        PIX(A3, A4, A5, B3, B4, B5, C3, C4, C5, vs3, fxf3);
    };

    // Sequence: step n loads row band-3+n (slot n&3), ingests row band-5+n
    // (ring slot (n-2)&7), emits row n-8. Prologue n=0..7 peeled:
    LOAD(band - 3, 0);
    LOAD(band - 2, 1);
    LOAD(band - 1, 2); INGEST(band - 3, 0, 0);
    LOAD(band + 0, 3); INGEST(band - 2, 1, 1);
    LOAD(band + 1, 0); INGEST(band - 1, 2, 2);
    LOAD(band + 2, 1); INGEST(band + 0, 3, 3);
    LOAD(band + 3, 2); INGEST(band + 1, 0, 4);
    LOAD(band + 4, 3); INGEST(band + 2, 1, 5);

    // main: n = 8 .. BH+7 (nn multiple of 8 keeps every slot a constant)
    for (int nn = 8; nn < 8 + BH; nn += 8) {
        #pragma unroll
        for (int k = 0; k < 8; ++k) {
            int n = nn + k;
            if (n <= BH + 5) LOAD(band - 3 + n, k & 3);      // uniform guard
            INGEST(band - 5 + n, (k - 2) & 3, (k - 2) & 7);
            EMIT(n - 8, (k + 2) & 7, (k + 3) & 7, (k + 4) & 7);
        }
    }

    // wave reduce then block reduce
    #pragma unroll
    for (int off = 32; off > 0; off >>= 1) acc += __shfl_down(acc, off);
    if (lane == 0) red[wvi] = acc;
    __syncthreads();
    if (tid == 0) atomicAdd(&scores[ch], red[0] + red[1] + red[2] + red[3]);
#undef PIX
}

// ---------------------------------------------------------------------------
// fuse_kernel: out[b] = sum_s w[b,s]*logits[b,s]; nontemporal, 2 float4/thread
// ---------------------------------------------------------------------------
__global__ __launch_bounds__(256)
void fuse_kernel(const float* __restrict__ logits,
                 const float* __restrict__ scores,
                 const float* __restrict__ lw,
                 float* __restrict__ out) {
    const size_t HW4 = (size_t)(H * W) / 4;     // 2^18 float4s per image

    float l0 = lw[0], l1 = lw[1], l2 = lw[2];
    float mx = fmaxf(l0, fmaxf(l1, l2));
    float e0 = __expf(l0 - mx), e1 = __expf(l1 - mx), e2 = __expf(l2 - mx);
    float inv = 1.f / (e0 + e1 + e2);
    float wl0 = e0 * inv, wl1 = e1 * inv, wl2 = e2 * inv;

    size_t t = (size_t)blockIdx.x * 256 + threadIdx.x;   // < 2^21
    #pragma unroll
    for (int it = 0; it < 2; ++it) {
        size_t i = t + ((size_t)it << 21);               // < 2^22 = NB*HW4
        size_t b = i >> 18;
        size_t r = i & (HW4 - 1);
        float s0 = scores[b * 3 + 0], s1 = scores[b * 3 + 1], s2 = scores[b * 3 + 2];
        float itot = 1.f / (s0 + s1 + s2 + 1e-6f);
        float w0 = 0.5f * (s0 * itot + wl0);
        float w1 = 0.5f * (s1 * itot + wl1);
        float w2 = 0.5f * (s2 * itot + wl2);
        const nfloat4* base = (const nfloat4*)logits + b * 3 * HW4 + r;
        nfloat4 x0 = __builtin_nontemporal_load(base);
        nfloat4 x1 = __builtin_nontemporal_load(base + HW4);
        nfloat4 x2 = __builtin_nontemporal_load(base + 2 * HW4);
        nfloat4 o = x0 * w0 + x1 * w1 + x2 * w2;
        __builtin_nontemporal_store(o, (nfloat4*)out + i);
    }
}

extern "C" void kernel_launch(void* const* d_in, const int* in_sizes, int n_in,
                              void* d_out, int out_size, void* d_ws, size_t ws_size,
                              hipStream_t stream) {
    const float* logits = (const float*)d_in[0];
    const float* lw     = (const float*)d_in[1];
    float* out    = (float*)d_out;
    float* scores = (float*)d_ws;    // 48 floats

    (void)hipMemsetAsync(d_ws, 0, NCH * sizeof(float), stream);

    dim3 g1(H / BH, NCH);            // (32, 48) = 1536 blocks; 2/CU resident -> 3 clean rounds
    score_kernel<<<g1, 256, 0, stream>>>(logits, scores);

    fuse_kernel<<<8192, 256, 0, stream>>>(logits, scores, lw, out);
}